// Round 3
// baseline (197.550 us; speedup 1.0000x reference)
//
#include <hip/hip_runtime.h>
#include <hip/hip_bf16.h>

#define E 2
#define N 512
#define B 64
#define T 12
#define K 64
#define NB 4  // n-rows per block in k_main (amortizes nodes reads)

// sup[e,n,m] = supports[e,n,m] + sum_k u[e,n,k] * (s[e,k]*softplus(bias[e,k])) * v[e,m,k]
__global__ __launch_bounds__(512)
void k_sup(const float* __restrict__ supports, const float* __restrict__ uu,
           const float* __restrict__ ss, const float* __restrict__ vv,
           const float* __restrict__ bias, float* __restrict__ sup) {
    const int en = blockIdx.x;
    const int e = en >> 9, n = en & (N - 1);
    __shared__ float uls[K];
    const int tid = threadIdx.x;
    if (tid < K) {
        float uf = uu[(size_t)(e * N + n) * K + tid];
        float sf = ss[e * K + tid];
        float bb = bias[e * K + tid];
        // numerically-stable softplus in fp32
        float sp = (bb > 0.f) ? (bb + log1pf(expf(-bb))) : log1pf(expf(bb));
        uls[tid] = uf * sf * sp;
    }
    __syncthreads();
    const int m = tid;
    const float4* vp = reinterpret_cast<const float4*>(vv + (size_t)(e * N + m) * K);
    float acc = 0.f;
#pragma unroll
    for (int i = 0; i < 16; ++i) {
        float4 q = vp[i];
        const float* w = &uls[i * 4];
        acc += w[0] * q.x + w[1] * q.y + w[2] * q.z + w[3] * q.w;
    }
    const size_t o = (size_t)(e * N + n) * N + m;
    sup[o] = acc + supports[o];
}

// nodes[b,n,t] = normalize_t( inputs[b,t,n,0] )
__global__ __launch_bounds__(256)
void k_nodes(const float* __restrict__ inp, float* __restrict__ nodes) {
    const int idx = blockIdx.x * 256 + threadIdx.x;  // b*N + n, total B*N = 32768
    const int b = idx >> 9, n = idx & (N - 1);
    float x[T];
    float sq = 0.f;
#pragma unroll
    for (int t = 0; t < T; ++t) {
        float xv = inp[((size_t)(b * T + t) * N + n) * 2];
        x[t] = xv;
        sq += xv * xv;
    }
    float inv = 1.f / fmaxf(sqrtf(sq), 1e-12f);
#pragma unroll
    for (int t = 0; t < T; ++t) nodes[(size_t)idx * T + t] = x[t] * inv;
}

// out[e,b,n,m] = relu(sup[e,n,m] * (exp(-dist(nodes[b,n],nodes[b,m])) + 1)), L1-normalized over m
__global__ __launch_bounds__(512)
void k_main(const float* __restrict__ sup, const float* __restrict__ nodes,
            float* __restrict__ out) {
    const int bi = blockIdx.x;       // B * (N/NB) = 8192 blocks
    const int b = bi >> 7;           // / (N/NB)
    const int n0 = (bi & 127) * NB;
    const int m = threadIdx.x;       // 0..511

    __shared__ float an[NB][T];
    __shared__ float red0[8], red1[8];
    __shared__ float invs[2];

    // this thread's node row (12 floats, 16B-aligned)
    float r[T];
    const float4* np4 = reinterpret_cast<const float4*>(nodes + (size_t)(b * N + m) * T);
    float4 q0 = np4[0], q1 = np4[1], q2 = np4[2];
    r[0] = q0.x; r[1] = q0.y; r[2]  = q0.z; r[3]  = q0.w;
    r[4] = q1.x; r[5] = q1.y; r[6]  = q1.z; r[7]  = q1.w;
    r[8] = q2.x; r[9] = q2.y; r[10] = q2.z; r[11] = q2.w;

    if ((unsigned)(m - n0) < NB) {
#pragma unroll
        for (int t = 0; t < T; ++t) an[m - n0][t] = r[t];
    }
    __syncthreads();

#pragma unroll
    for (int j = 0; j < NB; ++j) {
        const int n = n0 + j;
        float d2 = 0.f;
#pragma unroll
        for (int t = 0; t < T; ++t) {
            float d = r[t] - an[j][t];
            d2 += d * d;
        }
        float dist = (d2 > 0.f) ? sqrtf(d2) : 0.f;
        float dynp1 = __expf(-dist) + 1.f;

        float v0 = fmaxf(sup[(size_t)(0 * N + n) * N + m] * dynp1, 0.f);
        float v1 = fmaxf(sup[(size_t)(1 * N + n) * N + m] * dynp1, 0.f);

        // block L1-sum reduction: wave64 shfl tree then LDS combine
        float s0 = v0, s1 = v1;
#pragma unroll
        for (int off = 32; off > 0; off >>= 1) {
            s0 += __shfl_down(s0, off);
            s1 += __shfl_down(s1, off);
        }
        const int wave = m >> 6, lane = m & 63;
        if (lane == 0) { red0[wave] = s0; red1[wave] = s1; }
        __syncthreads();
        if (m == 0) {
            float t0 = 0.f, t1 = 0.f;
#pragma unroll
            for (int w = 0; w < 8; ++w) { t0 += red0[w]; t1 += red1[w]; }
            invs[0] = 1.f / fmaxf(t0, 1e-12f);
            invs[1] = 1.f / fmaxf(t1, 1e-12f);
        }
        __syncthreads();

        const size_t o0 = ((size_t)(0 * B + b) * N + n) * N + m;
        const size_t o1 = ((size_t)(1 * B + b) * N + n) * N + m;
        out[o0] = v0 * invs[0];
        out[o1] = v1 * invs[1];
    }
}

extern "C" void kernel_launch(void* const* d_in, const int* in_sizes, int n_in,
                              void* d_out, int out_size, void* d_ws, size_t ws_size,
                              hipStream_t stream) {
    const float* supports = (const float*)d_in[0];  // [E,N,N] fp32
    const float* uu       = (const float*)d_in[1];  // [E,N,K]
    const float* ss       = (const float*)d_in[2];  // [E,K]
    const float* vv       = (const float*)d_in[3];  // [E,N,K]
    const float* bias     = (const float*)d_in[4];  // [E,K]
    const float* inp      = (const float*)d_in[5];  // [B,T,N,2]
    float* out = (float*)d_out;                     // [E,B,N,N] fp32

    float* sup   = (float*)d_ws;                // 2*512*512 fp32 = 2 MiB
    float* nodes = sup + (size_t)E * N * N;     // 64*512*12 fp32 = 1.5 MiB

    k_sup  <<<E * N,        512, 0, stream>>>(supports, uu, ss, vv, bias, sup);
    k_nodes<<<(B * N) / 256, 256, 0, stream>>>(inp, nodes);
    k_main <<<B * (N / NB), 512, 0, stream>>>(sup, nodes, out);
}

// Round 4
// 169.985 us; speedup vs baseline: 1.1622x; 1.1622x over previous
//
#include <hip/hip_runtime.h>

#define E 2
#define N 512
#define B 64
#define T 12
#define K 64
#define NB 4

// ---- DPP wave-64 sum (VALU pipe, no DS traffic). rocPRIM idiom:
// row_shr 1,2,4,8 -> lane15 of each 16-lane row holds row sum;
// row_bcast15 (rows 1,3) -> lane31/lane63 hold 32-lane sums;
// row_bcast31 (rows 2,3) -> lane63 holds full sum; readlane(63) broadcasts.
template<int CTRL, int RM>
__device__ __forceinline__ float dpp_add(float x) {
    int y = __builtin_amdgcn_update_dpp(0, __float_as_int(x), CTRL, RM, 0xf, true);
    return x + __int_as_float(y);
}
__device__ __forceinline__ float wave_sum64(float x) {
    x = dpp_add<0x111, 0xf>(x);
    x = dpp_add<0x112, 0xf>(x);
    x = dpp_add<0x114, 0xf>(x);
    x = dpp_add<0x118, 0xf>(x);
    x = dpp_add<0x142, 0xa>(x);
    x = dpp_add<0x143, 0xc>(x);
    return __int_as_float(__builtin_amdgcn_readlane(__float_as_int(x), 63));
}

// Fused prep: blocks [0,256) compute sup (4 n-rows per block, v-row loads
// amortized 4x); blocks [256,320) compute normalized nodes.
__global__ __launch_bounds__(512)
void k_prep(const float* __restrict__ supports, const float* __restrict__ uu,
            const float* __restrict__ ss, const float* __restrict__ vv,
            const float* __restrict__ bias, const float* __restrict__ inp,
            float* __restrict__ sup, float* __restrict__ nodes) {
    const int blk = blockIdx.x;
    const int tid = threadIdx.x;
    if (blk < 2 * (N / NB)) {
        const int e = blk >> 7;
        const int n0 = (blk & 127) * NB;
        __shared__ float uls[NB][K];
        if (tid < NB * K) {
            const int j = tid >> 6, k = tid & 63;
            float bb = bias[e * K + k];
            float sp_ = (bb > 0.f) ? (bb + log1pf(expf(-bb))) : log1pf(expf(bb));
            uls[j][k] = uu[(size_t)(e * N + n0 + j) * K + k] * ss[e * K + k] * sp_;
        }
        __syncthreads();
        const int m = tid;
        const float4* vp = reinterpret_cast<const float4*>(vv + (size_t)(e * N + m) * K);
        float accs[NB] = {0.f, 0.f, 0.f, 0.f};
#pragma unroll
        for (int i = 0; i < 16; ++i) {
            float4 q = vp[i];
#pragma unroll
            for (int j = 0; j < NB; ++j) {
                const float* w = &uls[j][i * 4];
                accs[j] += w[0] * q.x + w[1] * q.y + w[2] * q.z + w[3] * q.w;
            }
        }
#pragma unroll
        for (int j = 0; j < NB; ++j) {
            const size_t o = (size_t)(e * N + n0 + j) * N + m;
            sup[o] = accs[j] + supports[o];
        }
    } else {
        const int idx = (blk - 2 * (N / NB)) * 512 + tid;  // 0..32767 = b*N+n
        const int b = idx >> 9, n = idx & (N - 1);
        float x[T];
        float sq = 0.f;
#pragma unroll
        for (int t = 0; t < T; ++t) {
            float xv = inp[((size_t)(b * T + t) * N + n) * 2];
            x[t] = xv;
            sq += xv * xv;
        }
        float inv = 1.f / fmaxf(sqrtf(sq), 1e-12f);
#pragma unroll
        for (int t = 0; t < T; ++t) nodes[(size_t)idx * T + t] = x[t] * inv;
    }
}

// out[e,b,n,m] = relu(sup[e,n,m]*(exp(-||x_n-x_m||)+1)), L1-normalized over m.
// Thread owns column m; anchors read via wave-uniform (scalar) loads; DPP
// reduction on VALU pipe; 2 barriers per block total.
__global__ __launch_bounds__(512)
void k_main(const float* __restrict__ sup, const float* __restrict__ nodes,
            float* __restrict__ out) {
    const int bi = blockIdx.x;       // B * (N/NB) = 8192
    const int b = bi >> 7;
    const int n0 = (bi & 127) * NB;
    const int m = threadIdx.x;
    const int wave = m >> 6, lane = m & 63;

    __shared__ float red[8 * 8];
    __shared__ float invs[8];

    // own node row (12 floats, 48B-aligned)
    const float4* np4 = reinterpret_cast<const float4*>(nodes + (size_t)(b * N + m) * T);
    float4 q0 = np4[0], q1 = np4[1], q2 = np4[2];
    float r[T] = {q0.x, q0.y, q0.z, q0.w, q1.x, q1.y, q1.z, q1.w, q2.x, q2.y, q2.z, q2.w};

    // anchor rows n0..n0+3: wave-uniform address -> scalar loads, no LDS
    const float* __restrict__ anc = nodes + (size_t)(b * N + n0) * T;

    // prefetch all sup values (coalesced, independent of node math)
    float sp[NB][2];
#pragma unroll
    for (int j = 0; j < NB; ++j) {
        sp[j][0] = sup[(size_t)(n0 + j) * N + m];
        sp[j][1] = sup[(size_t)(N + n0 + j) * N + m];
    }

    float v[NB][2];
#pragma unroll
    for (int j = 0; j < NB; ++j) {
        float d2 = 0.f;
#pragma unroll
        for (int t = 0; t < T; ++t) {
            float d = r[t] - anc[j * T + t];
            d2 += d * d;
        }
        float dist = (d2 > 0.f) ? sqrtf(d2) : 0.f;
        float f = __expf(-dist) + 1.f;
        v[j][0] = fmaxf(sp[j][0] * f, 0.f);
        v[j][1] = fmaxf(sp[j][1] * f, 0.f);
    }

    // per-wave sums (VALU DPP), one LDS write per (wave, group)
#pragma unroll
    for (int j = 0; j < NB; ++j) {
#pragma unroll
        for (int e = 0; e < 2; ++e) {
            float tot = wave_sum64(v[j][e]);
            if (lane == 0) red[wave * 8 + j * 2 + e] = tot;
        }
    }
    __syncthreads();
    if (wave == 0) {
        float t = red[lane];             // lane = w'*8 + g
        t += __shfl_xor(t, 8);
        t += __shfl_xor(t, 16);
        t += __shfl_xor(t, 32);          // now every lane holds total for its g
        if (lane < 8) invs[lane] = 1.f / fmaxf(t, 1e-12f);
    }
    __syncthreads();

#pragma unroll
    for (int j = 0; j < NB; ++j) {
#pragma unroll
        for (int e = 0; e < 2; ++e) {
            out[((size_t)(e * B + b) * N + n0 + j) * N + m] = v[j][e] * invs[j * 2 + e];
        }
    }
}

extern "C" void kernel_launch(void* const* d_in, const int* in_sizes, int n_in,
                              void* d_out, int out_size, void* d_ws, size_t ws_size,
                              hipStream_t stream) {
    const float* supports = (const float*)d_in[0];  // [E,N,N] fp32
    const float* uu       = (const float*)d_in[1];  // [E,N,K]
    const float* ss       = (const float*)d_in[2];  // [E,K]
    const float* vv       = (const float*)d_in[3];  // [E,N,K]
    const float* bias     = (const float*)d_in[4];  // [E,K]
    const float* inp      = (const float*)d_in[5];  // [B,T,N,2]
    float* out = (float*)d_out;                     // [E,B,N,N] fp32

    float* sup   = (float*)d_ws;                // 2 MiB
    float* nodes = sup + (size_t)E * N * N;     // 1.5 MiB

    k_prep<<<2 * (N / NB) + (B * N) / 512, 512, 0, stream>>>(
        supports, uu, ss, vv, bias, inp, sup, nodes);
    k_main<<<B * (N / NB), 512, 0, stream>>>(sup, nodes, out);
}